// Round 4
// baseline (852.492 us; speedup 1.0000x reference)
//
#include <hip/hip_runtime.h>
#include <stdint.h>

#define HASH_BITS 19
#define HASH_SIZE (1u << HASH_BITS)
// 8 slices = top 3 hash bits. One slice = 64K entries * 32B = 2 MiB, fits a
// single XCD's 4 MiB L2. blockIdx&7 -> XCD (round-robin dispatch), so in P2
// every gather issued by XCD s falls inside slice s -> L2-resident.
#define SLICE_SHIFT (HASH_BITS - 3)
#define NSLICE 8

#define GROUP_BITS 13
#define GROUP (1 << GROUP_BITS)     // 8192 items per group (N=2^23 -> 1024 groups)
#define BLOCK 256
#define IPT (GROUP / BLOCK)         // 32 items/thread in P1

typedef float vfloat2 __attribute__((ext_vector_type(2)));
typedef float vfloat4 __attribute__((ext_vector_type(4)));

__device__ __forceinline__ uint32_t bitmix_hash(float qx, float qy) {
    // q in [0,4096): float->uint truncation == floor; all intermediates
    // positive and < 2^63, so uint64 arithmetic == reference int64 exactly.
    uint64_t ix = (uint64_t)(uint32_t)qx;
    uint64_t iy = (uint64_t)(uint32_t)qy;
    uint64_t hh = ix;
    hh ^= hh >> 16;
    hh *= 2246822507ull;
    hh ^= hh >> 13;
    hh += iy * 3266489909ull;
    hh ^= hh >> 16;
    return (uint32_t)hh & (HASH_SIZE - 1);
}

// ---- P1: hash + bucket records by (group, slice). One block per group. ----
// Ballot-based counting/placement: no LDS-atomic storms, no global atomics,
// deterministic layout. Records for group g live at records[g*GROUP ...],
// sub-bucketed by slice; hdr[g*8+s] = exclusive base of slice s in the group.
__global__ __launch_bounds__(BLOCK) void bucket_kernel(
    const vfloat2* __restrict__ pos,   // N float2
    uint32_t* __restrict__ records,    // n u32 (ws)
    uint32_t* __restrict__ hdr,        // ngroups*8 u32 (ws)
    long long n)
{
    __shared__ uint32_t cnt[BLOCK / 64][NSLICE];
    __shared__ uint32_t scan[BLOCK / 64][NSLICE];
    const int g = blockIdx.x;
    const long long gbase = (long long)g << GROUP_BITS;
    const int tid = threadIdx.x;
    const int w = tid >> 6;
    const int lane = tid & 63;
    const uint64_t lt_mask = (lane == 63) ? ~0ull >> 1 : ((1ull << (lane + 1)) >> 1) - 0;
    // ((1ull<<lane)-1) without UB concerns:
    const uint64_t lt = (lane == 0) ? 0ull : (~0ull >> (64 - lane));
    (void)lt_mask;

    // 1) stream pos once, hash into registers (invalid -> idx=~0 -> slice>7)
    uint32_t idx[IPT];
#pragma unroll
    for (int j = 0; j < IPT; ++j) {
        long long item = gbase + j * BLOCK + tid;
        if (item < n) {
            vfloat2 q = __builtin_nontemporal_load(&pos[item]);
            idx[j] = bitmix_hash(q.x, q.y);
        } else {
            idx[j] = 0xFFFFFFFFu;
        }
    }

    // 2) per-(wave, slice) counts via ballots
    uint32_t c[NSLICE] = {0, 0, 0, 0, 0, 0, 0, 0};
#pragma unroll
    for (int j = 0; j < IPT; ++j) {
        uint32_t sl = idx[j] >> SLICE_SHIFT;
#pragma unroll
        for (uint32_t s0 = 0; s0 < NSLICE; ++s0)
            c[s0] += (uint32_t)__popcll(__ballot(sl == s0));
    }
    if (lane == 0) {
#pragma unroll
        for (int s0 = 0; s0 < NSLICE; ++s0) cnt[w][s0] = c[s0];
    }
    __syncthreads();

    // 3) exclusive scan over (slice, wave); publish per-slice bases to hdr
    if (tid == 0) {
        uint32_t run = 0;
        for (int s0 = 0; s0 < NSLICE; ++s0) {
            hdr[(size_t)g * NSLICE + s0] = run;
            for (int w0 = 0; w0 < BLOCK / 64; ++w0) {
                scan[w0][s0] = run;
                run += cnt[w0][s0];
            }
        }
    }
    __syncthreads();

    uint32_t off[NSLICE];
#pragma unroll
    for (int s0 = 0; s0 < NSLICE; ++s0) off[s0] = scan[w][s0];

    // 4) place records: rank within wave via ballot prefix
#pragma unroll
    for (int j = 0; j < IPT; ++j) {
        uint32_t sl = idx[j] >> SLICE_SHIFT;
        uint32_t lid = (uint32_t)(j * BLOCK + tid);   // 13 bits
#pragma unroll
        for (uint32_t s0 = 0; s0 < NSLICE; ++s0) {
            uint64_t m = __ballot(sl == s0);
            if (sl == s0) {
                uint32_t rank = (uint32_t)__popcll(m & lt);
                records[gbase + off[s0] + rank] = (lid << HASH_BITS) | idx[j];
            }
            off[s0] += (uint32_t)__popcll(m);
        }
    }
}

// ---- P2: XCD-routed gather + scatter-store. Block (g, s=blockIdx&7). ----
// All gathers of this block hit slice s (XCD-local L2). Every lane does
// useful work (records are pre-bucketed -- no predicated scan). The 8 sibling
// blocks of group g run ~concurrently, so both 32B halves of each out line
// are written close in time -> MALL merges partial lines.
__global__ __launch_bounds__(BLOCK) void gather_kernel(
    const uint32_t* __restrict__ records,
    const uint32_t* __restrict__ hdr,
    const vfloat4* __restrict__ table, // HASH_SIZE*2 float4
    vfloat4* __restrict__ out,         // 2N float4
    long long n)
{
    const uint32_t s = blockIdx.x & (NSLICE - 1);
    const uint32_t g = blockIdx.x >> 3;
    const long long gbase = (long long)g << GROUP_BITS;
    long long rem = n - gbase;
    uint32_t gvalid = rem >= GROUP ? (uint32_t)GROUP : (uint32_t)rem;
    uint32_t b = hdr[(size_t)g * NSLICE + s];
    uint32_t e = (s == NSLICE - 1) ? gvalid : hdr[(size_t)g * NSLICE + s + 1];

    for (uint32_t i = threadIdx.x + b; i < e; i += BLOCK) {
        uint32_t rec = __builtin_nontemporal_load(&records[gbase + i]);
        uint32_t id = rec & (HASH_SIZE - 1);
        uint32_t lid = rec >> HASH_BITS;
        vfloat4 lo = table[(size_t)id * 2];        // L2-resident slice
        vfloat4 hi = table[(size_t)id * 2 + 1];
        size_t o = (size_t)(gbase + lid) * 2;
        __builtin_nontemporal_store(lo, &out[o]);
        __builtin_nontemporal_store(hi, &out[o + 1]);
    }
}

// ---- fallback: round-1 single-kernel (if ws too small) ----
__global__ __launch_bounds__(256) void hashgrid2d_fallback(
    const vfloat2* __restrict__ pos,
    const vfloat4* __restrict__ table,
    vfloat4* __restrict__ out,
    long long n)
{
    long long t = (long long)blockIdx.x * blockDim.x + threadIdx.x;
    long long nitems = 2LL * n;
    long long stride = (long long)gridDim.x * blockDim.x;
    for (; t < nitems; t += stride) {
        long long p = t >> 1;
        int h = (int)(t & 1);
        vfloat2 q = __builtin_nontemporal_load(&pos[p]);
        uint32_t id = bitmix_hash(q.x, q.y);
        vfloat4 vv = table[(size_t)id * 2 + h];
        __builtin_nontemporal_store(vv, &out[(size_t)p * 2 + h]);
    }
}

extern "C" void kernel_launch(void* const* d_in, const int* in_sizes, int n_in,
                              void* d_out, int out_size, void* d_ws, size_t ws_size,
                              hipStream_t stream) {
    const vfloat2* pos   = (const vfloat2*)d_in[0];   // positions [N,2]
    const vfloat4* table = (const vfloat4*)d_in[1];   // table [HASH_SIZE,8]
    vfloat4* out         = (vfloat4*)d_out;           // [N,8] as 2N float4

    long long n = in_sizes[0] / 2;  // N positions
    if (n <= 0) return;

    long long ngroups = (n + GROUP - 1) >> GROUP_BITS;
    size_t need = (size_t)n * 4 + (size_t)ngroups * NSLICE * 4;

    if (ws_size >= need && ngroups <= 0x7FFFFFFFLL / NSLICE) {
        uint32_t* records = (uint32_t*)d_ws;
        uint32_t* hdr     = (uint32_t*)((char*)d_ws + (size_t)n * 4);

        bucket_kernel<<<(int)ngroups, BLOCK, 0, stream>>>(pos, records, hdr, n);
        gather_kernel<<<(int)(ngroups * NSLICE), BLOCK, 0, stream>>>(
            records, hdr, table, out, n);
    } else {
        long long nitems = 2LL * n;
        int block = 256;
        long long needb = (nitems + block - 1) / block;
        int grid = (int)(needb < 2048 ? needb : 2048);
        hashgrid2d_fallback<<<grid, block, 0, stream>>>(pos, table, out, n);
    }
}

// Round 5
// 576.991 us; speedup vs baseline: 1.4775x; 1.4775x over previous
//
#include <hip/hip_runtime.h>
#include <stdint.h>

#define HASH_BITS 19
#define HASH_SIZE (1u << HASH_BITS)

typedef float vfloat2 __attribute__((ext_vector_type(2)));
typedef float vfloat4 __attribute__((ext_vector_type(4)));

__device__ __forceinline__ uint32_t bitmix_hash(float qx, float qy) {
    // q in [0,4096): float->uint truncation == floor; all intermediates
    // positive and < 2^63, so uint64 arithmetic == reference int64 exactly.
    uint64_t ix = (uint64_t)(uint32_t)qx;
    uint64_t iy = (uint64_t)(uint32_t)qy;
    uint64_t hh = ix;
    hh ^= hh >> 16;
    hh *= 2246822507ull;
    hh ^= hh >> 13;
    hh += iy * 3266489909ull;
    hh ^= hh >> 16;
    return (uint32_t)hh & (HASH_SIZE - 1);
}

// One thread per OUTPUT LINE (2 items = 64B):
//  - pos read once per item as one float4 per thread (R1's half-entry split
//    read each float2 twice -> this cuts ~34-58 MB of pos fetch)
//  - 4 independent 16B table gathers in flight per thread (2x the MLP of the
//    half-entry form; the +1 consecutive 16B of each entry is an L1 hit, so
//    distinct-line traffic is unchanged)
//  - stores a FULL 64B line per thread (4x16B consecutive, wave-contiguous):
//    the friendliest HBM write pattern; no partial-line effects anywhere.
// Table loads stay regular (cacheable) -- the 16 MiB table is the only
// reused data; pos/out streams are nontemporal so they don't evict it.
__global__ __launch_bounds__(256) void hashgrid2d_pair(
    const vfloat4* __restrict__ pos4,  // npairs float4 = 2 positions each
    const vfloat4* __restrict__ table, // HASH_SIZE*2 float4
    vfloat4* __restrict__ out,         // 2N float4
    long long npairs)
{
    long long t = (long long)blockIdx.x * blockDim.x + threadIdx.x;
    if (t >= npairs) return;

    vfloat4 q = __builtin_nontemporal_load(&pos4[t]);
    uint32_t i0 = bitmix_hash(q.x, q.y);
    uint32_t i1 = bitmix_hash(q.z, q.w);

    // 4 independent gathers issued back-to-back
    vfloat4 a = table[(size_t)i0 * 2];
    vfloat4 b = table[(size_t)i0 * 2 + 1];
    vfloat4 c = table[(size_t)i1 * 2];
    vfloat4 d = table[(size_t)i1 * 2 + 1];

    size_t o = (size_t)t * 4;
    __builtin_nontemporal_store(a, &out[o]);
    __builtin_nontemporal_store(b, &out[o + 1]);
    __builtin_nontemporal_store(c, &out[o + 2]);
    __builtin_nontemporal_store(d, &out[o + 3]);
}

// Tail (odd N): handle the final lone position.
__global__ void hashgrid2d_tail(
    const vfloat2* __restrict__ pos,
    const vfloat4* __restrict__ table,
    vfloat4* __restrict__ out,
    long long item)
{
    vfloat2 q = pos[item];
    uint32_t id = bitmix_hash(q.x, q.y);
    out[(size_t)item * 2]     = table[(size_t)id * 2];
    out[(size_t)item * 2 + 1] = table[(size_t)id * 2 + 1];
}

extern "C" void kernel_launch(void* const* d_in, const int* in_sizes, int n_in,
                              void* d_out, int out_size, void* d_ws, size_t ws_size,
                              hipStream_t stream) {
    const vfloat2* pos   = (const vfloat2*)d_in[0];   // positions [N,2]
    const vfloat4* table = (const vfloat4*)d_in[1];   // table [HASH_SIZE,8]
    vfloat4* out         = (vfloat4*)d_out;           // [N,8] as 2N float4

    long long n = in_sizes[0] / 2;  // N positions
    if (n <= 0) return;

    long long npairs = n >> 1;
    if (npairs > 0) {
        int block = 256;
        long long grid = (npairs + block - 1) / block;
        hashgrid2d_pair<<<(int)grid, block, 0, stream>>>(
            (const vfloat4*)pos, table, out, npairs);
    }
    if (n & 1) {
        hashgrid2d_tail<<<1, 1, 0, stream>>>(pos, table, out, n - 1);
    }
}